// Round 1
// baseline (452.822 us; speedup 1.0000x reference)
//
#include <hip/hip_runtime.h>

// Problem constants
#define Bn   4
#define Cc   256
#define Hh   128
#define Ww   256
#define HWp  32768          // H*W
#define CQK  64
#define COUT 256

typedef _Float16 half8 __attribute__((ext_vector_type(8)));
typedef _Float16 half4 __attribute__((ext_vector_type(4)));
typedef float   floatx4 __attribute__((ext_vector_type(4)));

#define MFMA16(a, b, c) __builtin_amdgcn_mfma_f32_16x16x32_f16((a), (b), (c), 0, 0, 0)

// ---------------------------------------------------------------------------
// Kernel 1: Q/K/V 1x1-conv projections (fp32 NCHW inputs -> f16 ws tensors)
//   Qws, Kws: pixel-major [b][pix][64]   (pix = h*W + w)
//   Vws:      channel-major [b][o][pix]
// grid: (512 pixel-tiles of 64, B, 2 jobs: 0=Q from de_out, 1=K+V from flow)
// ---------------------------------------------------------------------------
__global__ __launch_bounds__(256) void k_qkv(
    const float* __restrict__ flow, const float* __restrict__ de_out,
    const float* __restrict__ Wq, const float* __restrict__ bq,
    const float* __restrict__ Wk, const float* __restrict__ bk,
    const float* __restrict__ Wv, const float* __restrict__ bv,
    _Float16* __restrict__ Qws, _Float16* __restrict__ Kws,
    _Float16* __restrict__ Vws)
{
    __shared__ __align__(16) _Float16 x_lds[64 * 264];  // [pix][c], pitch 264
    __shared__ __align__(16) _Float16 w_lds[32 * 264];  // [m][c],  pitch 264

    const int t   = threadIdx.x;
    const int b   = blockIdx.y;
    const int job = blockIdx.z;
    const int pb  = blockIdx.x * 64;  // pixel base in [0, HW)

    const float* X = (job == 0 ? de_out : flow) + (size_t)b * Cc * HWp;

    // ---- stage X tile: [256 c][64 px] fp32 -> transposed f16 x_lds[px][c]
    {
        const int px4 = t & 15;   // pixel quad index
        const int cg  = t >> 4;   // 0..15
        for (int rep = 0; rep < 4; ++rep) {
            const int c0 = 4 * cg + 64 * rep;
            float4 r0 = *(const float4*)&X[(size_t)(c0 + 0) * HWp + pb + 4 * px4];
            float4 r1 = *(const float4*)&X[(size_t)(c0 + 1) * HWp + pb + 4 * px4];
            float4 r2 = *(const float4*)&X[(size_t)(c0 + 2) * HWp + pb + 4 * px4];
            float4 r3 = *(const float4*)&X[(size_t)(c0 + 3) * HWp + pb + 4 * px4];
            half4 h;
            h = (half4){(_Float16)r0.x, (_Float16)r1.x, (_Float16)r2.x, (_Float16)r3.x};
            *(half4*)&x_lds[(4 * px4 + 0) * 264 + c0] = h;
            h = (half4){(_Float16)r0.y, (_Float16)r1.y, (_Float16)r2.y, (_Float16)r3.y};
            *(half4*)&x_lds[(4 * px4 + 1) * 264 + c0] = h;
            h = (half4){(_Float16)r0.z, (_Float16)r1.z, (_Float16)r2.z, (_Float16)r3.z};
            *(half4*)&x_lds[(4 * px4 + 2) * 264 + c0] = h;
            h = (half4){(_Float16)r0.w, (_Float16)r1.w, (_Float16)r2.w, (_Float16)r3.w};
            *(half4*)&x_lds[(4 * px4 + 3) * 264 + c0] = h;
        }
    }

    const int nmt  = (job == 0) ? 2 : 10;
    const int wv   = t >> 6;
    const int lane = t & 63;
    const int quad = lane >> 4;
    const int l16  = lane & 15;

    for (int mt = 0; mt < nmt; ++mt) {
        const float* Wsel;
        const float* bsel;
        int mbase, dstmode;
        _Float16* dst;
        if (job == 0)      { Wsel = Wq; bsel = bq; mbase = mt * 32;        dst = Qws; dstmode = 0; }
        else if (mt < 2)   { Wsel = Wk; bsel = bk; mbase = mt * 32;        dst = Kws; dstmode = 0; }
        else               { Wsel = Wv; bsel = bv; mbase = (mt - 2) * 32;  dst = Vws; dstmode = 1; }

        __syncthreads();  // protect w_lds reuse (also covers x_lds first use)
        // stage W rows [mbase, mbase+32) x 256 fp32 -> f16 w_lds
        for (int i = 0; i < 8; ++i) {
            const int f4  = t + 256 * i;          // 0..2047 float4s
            const int row = f4 >> 6;              // 64 float4 per row
            const int off = (f4 & 63) * 4;
            float4 w4 = *(const float4*)&Wsel[(size_t)(mbase + row) * 256 + off];
            half4 h = (half4){(_Float16)w4.x, (_Float16)w4.y, (_Float16)w4.z, (_Float16)w4.w};
            *(half4*)&w_lds[row * 264 + off] = h;
        }
        __syncthreads();

        // compute 32m x 64n: wave -> m16 = wv&1, n-pair = wv>>1
        const int mrow = 16 * (wv & 1) + l16;
        half8 a[8];
        for (int ks = 0; ks < 8; ++ks)
            a[ks] = *(const half8*)&w_lds[mrow * 264 + ks * 32 + quad * 8];

        const int n0 = (wv >> 1) * 32;
        floatx4 acc0 = {0.f, 0.f, 0.f, 0.f};
        floatx4 acc1 = {0.f, 0.f, 0.f, 0.f};
        for (int ks = 0; ks < 8; ++ks) {
            half8 b0 = *(const half8*)&x_lds[(n0 + l16) * 264 + ks * 32 + quad * 8];
            half8 b1 = *(const half8*)&x_lds[(n0 + 16 + l16) * 264 + ks * 32 + quad * 8];
            acc0 = MFMA16(a[ks], b0, acc0);
            acc1 = MFMA16(a[ks], b1, acc1);
        }

        // epilogue: D[row = quad*4+reg][col = l16], add bias, store f16
        const int mloc = 16 * (wv & 1) + quad * 4;
        float4 bi = *(const float4*)&bsel[mbase + mloc];
        const float bia[4] = {bi.x, bi.y, bi.z, bi.w};
        if (dstmode == 0) {
            // Q/K pixel-major: dst[(b*HW + pix)*64 + mt*32 + mloc + r]
            for (int nt = 0; nt < 2; ++nt) {
                floatx4 acc = nt ? acc1 : acc0;
                const int pix = pb + n0 + nt * 16 + l16;
                half4 h = (half4){(_Float16)(acc[0] + bia[0]), (_Float16)(acc[1] + bia[1]),
                                  (_Float16)(acc[2] + bia[2]), (_Float16)(acc[3] + bia[3])};
                *(half4*)&dst[((size_t)b * HWp + pix) * 64 + mt * 32 + mloc] = h;
            }
        } else {
            // V channel-major: dst[(b*256 + o)*HW + pix]
            for (int nt = 0; nt < 2; ++nt) {
                floatx4 acc = nt ? acc1 : acc0;
                const int pix = pb + n0 + nt * 16 + l16;
                for (int r = 0; r < 4; ++r) {
                    const int o = mbase + mloc + r;
                    dst[((size_t)b * 256 + o) * HWp + pix] = (_Float16)(acc[r] + bia[r]);
                }
            }
        }
    }
}

// ---------------------------------------------------------------------------
// Kernel 2: width-axial attention per (b,h) row.
// grid: (H, B), block 256 threads (4 waves), ~58.5 KB LDS -> 2 blocks/CU.
// Per 32-query-row chunk: E = q k^T (f16 MFMA) -> softmax (fp32) ->
// O^T tiles: A = v[o][w'], B = att[w][w'] so stores are w-contiguous.
// ---------------------------------------------------------------------------
__global__ __launch_bounds__(256) void k_attn(
    const _Float16* __restrict__ Qws, const _Float16* __restrict__ Kws,
    const _Float16* __restrict__ Vws, float* __restrict__ out)
{
    __shared__ __align__(16) _Float16 q_lds[32 * 72];    // [w][d]   pitch 72
    __shared__ __align__(16) _Float16 k_lds[256 * 72];   // [w'][d]  pitch 72; reused as v_lds[64][264]
    __shared__ __align__(16) _Float16 att_lds[32 * 264]; // [w][w']  pitch 264
    __shared__ float inv_l[32];

    const int t    = threadIdx.x;
    const int h    = blockIdx.x;
    const int b    = blockIdx.y;
    const int wv   = t >> 6;
    const int lane = t & 63;
    const int quad = lane >> 4;
    const int l16  = lane & 15;
    const size_t pixbase = (size_t)b * HWp + h * 256;

    for (int chunk = 0; chunk < 8; ++chunk) {
        __syncthreads();  // protect q/k(v)/att reuse from previous chunk
        // stage q: 32 rows x 64 d
        {
            const int row = t >> 3, off = (t & 7) * 8;
            *(half8*)&q_lds[row * 72 + off] =
                *(const half8*)&Qws[(pixbase + chunk * 32 + row) * 64 + off];
        }
        // stage k: 256 rows x 64 d
        for (int i = 0; i < 8; ++i) {
            const int g = t + 256 * i;
            const int row = g >> 3, off = (g & 7) * 8;
            *(half8*)&k_lds[row * 72 + off] =
                *(const half8*)&Kws[(pixbase + row) * 64 + off];
        }
        __syncthreads();

        // ---- energy: 32 x 256, wave: m-tile wv&1, n-tiles (wv>>1)*8 + j
        {
            const int mrow = 16 * (wv & 1) + l16;
            half8 a0 = *(const half8*)&q_lds[mrow * 72 + quad * 8];
            half8 a1 = *(const half8*)&q_lds[mrow * 72 + 32 + quad * 8];
            const int mb2 = 16 * (wv & 1) + quad * 4;
            for (int j = 0; j < 8; ++j) {
                const int nt = (wv >> 1) * 8 + j;
                half8 b0 = *(const half8*)&k_lds[(nt * 16 + l16) * 72 + quad * 8];
                half8 b1 = *(const half8*)&k_lds[(nt * 16 + l16) * 72 + 32 + quad * 8];
                floatx4 acc = {0.f, 0.f, 0.f, 0.f};
                acc = MFMA16(a0, b0, acc);
                acc = MFMA16(a1, b1, acc);
                for (int r = 0; r < 4; ++r)
                    att_lds[(mb2 + r) * 264 + nt * 16 + l16] = (_Float16)acc[r];
            }
        }
        __syncthreads();

        // ---- softmax over w' (256), 8 threads per row, fp32 math
        {
            const int r = t >> 3, seg = t & 7;
            _Float16* rowp = &att_lds[r * 264 + seg * 32];
            float vals[32];
            float mx = -1e30f;
            for (int i = 0; i < 32; ++i) { vals[i] = (float)rowp[i]; mx = fmaxf(mx, vals[i]); }
            mx = fmaxf(mx, __shfl_xor(mx, 1));
            mx = fmaxf(mx, __shfl_xor(mx, 2));
            mx = fmaxf(mx, __shfl_xor(mx, 4));
            float s = 0.f;
            for (int i = 0; i < 32; ++i) { vals[i] = __expf(vals[i] - mx); s += vals[i]; }
            s += __shfl_xor(s, 1);
            s += __shfl_xor(s, 2);
            s += __shfl_xor(s, 4);
            for (int i = 0; i < 32; ++i) rowp[i] = (_Float16)vals[i];
            if (seg == 0) inv_l[r] = 1.f / s;
        }
        __syncthreads();

        // ---- PV: O[o][w] = sum_w' v[o][w'] * att[w][w'], o staged 64 at a time
        _Float16* v_lds = k_lds;  // reuse region as [o][w'] pitch 264
        for (int os = 0; os < 4; ++os) {
            if (os) __syncthreads();
            for (int i = 0; i < 8; ++i) {
                const int g = t + 256 * i;
                const int row = g >> 5, off = (g & 31) * 8;
                *(half8*)&v_lds[row * 264 + off] =
                    *(const half8*)&Vws[((size_t)b * 256 + os * 64 + row) * HWp + h * 256 + off];
            }
            __syncthreads();

            floatx4 acc0 = {0.f, 0.f, 0.f, 0.f};
            floatx4 acc1 = {0.f, 0.f, 0.f, 0.f};
            for (int ks = 0; ks < 8; ++ks) {
                half8 a  = *(const half8*)&v_lds[(16 * wv + l16) * 264 + ks * 32 + quad * 8];
                half8 b0 = *(const half8*)&att_lds[l16 * 264 + ks * 32 + quad * 8];
                half8 b1 = *(const half8*)&att_lds[(16 + l16) * 264 + ks * 32 + quad * 8];
                acc0 = MFMA16(a, b0, acc0);
                acc1 = MFMA16(a, b1, acc1);
            }
            const float il0 = inv_l[l16];
            const float il1 = inv_l[16 + l16];
            const int og = os * 64 + 16 * wv + quad * 4;
            const int wg = chunk * 32 + l16;
            for (int r = 0; r < 4; ++r) {
                out[(((size_t)b * 256 + og + r) * Hh + h) * Ww + wg]      = acc0[r] * il0;
                out[(((size_t)b * 256 + og + r) * Hh + h) * Ww + 16 + wg] = acc1[r] * il1;
            }
        }
    }
}

// ---------------------------------------------------------------------------
extern "C" void kernel_launch(void* const* d_in, const int* in_sizes, int n_in,
                              void* d_out, int out_size, void* d_ws, size_t ws_size,
                              hipStream_t stream)
{
    const float* flow   = (const float*)d_in[0];
    const float* de_out = (const float*)d_in[1];
    const float* Wq = (const float*)d_in[2];
    const float* bq = (const float*)d_in[3];
    const float* Wk = (const float*)d_in[4];
    const float* bk = (const float*)d_in[5];
    const float* Wv = (const float*)d_in[6];
    const float* bv = (const float*)d_in[7];

    _Float16* Qws = (_Float16*)d_ws;
    _Float16* Kws = Qws + (size_t)Bn * HWp * 64;
    _Float16* Vws = Kws + (size_t)Bn * HWp * 64;
    float* out = (float*)d_out;

    dim3 g1(HWp / 64, Bn, 2);
    k_qkv<<<g1, 256, 0, stream>>>(flow, de_out, Wq, bq, Wk, bk, Wv, bv, Qws, Kws, Vws);

    dim3 g2(Hh, Bn);
    k_attn<<<g2, 256, 0, stream>>>(Qws, Kws, Vws, out);
}